// Round 12
// baseline (1141.182 us; speedup 1.0000x reference)
//
#include <hip/hip_runtime.h>
#include <math.h>

#pragma clang fp contract(fast)

#define S    612
#define TT   8192
#define NB   32
#define SPE  768          // emission row stride in floats (12 per lane, 16B aligned)

typedef float v2f __attribute__((ext_vector_type(2)));

// workspace layout (bytes)
#define WR_OFF    0        // 640 float4 = 10240 B  (w0, r1, r2, r3) per state
#define IV_OFF    10240    // 4 floats (I[s]/w0[s])
#define EMIS_OFF  16384    // 100*768 floats = 307200 B (pair-reordered, EW = E*w0)
#define OBS_OFF   327680   // 32*8192 ints = 1 MB

__device__ __forceinline__ void softrow(const float* tk, int r, float4& q) {
    float l0 = tk[3*r], l1 = tk[3*r+1], l2 = tk[3*r+2], l3 = 1.0f;
    float m = fmaxf(fmaxf(l0, l1), fmaxf(l2, l3));
    float e0 = expf(l0-m), e1 = expf(l1-m), e2 = expf(l2-m), e3 = expf(l3-m);
    float inv = 1.0f / (e0+e1+e2+e3);
    q = make_float4(e0*inv, e1*inv, e2*inv, e3*inv);
}

// gather form: wR[s] = (w0(s), w1(s-1)/w0(s), w2(s-2)/w0(s), w3(s-3)/w0(s))
__global__ __launch_bounds__(256) void prep_tables(
    const float* __restrict__ tk, const float* __restrict__ ik,
    float4* __restrict__ wR, float* __restrict__ IvecAdj)
{
    int i = blockIdx.x * 256 + threadIdx.x;
    if (i < S) {
        float4 qs, q1, q2, q3;
        softrow(tk, i, qs);
        softrow(tk, (i+S-1)%S, q1);
        softrow(tk, (i+S-2)%S, q2);
        softrow(tk, (i+S-3)%S, q3);
        float inv0 = 1.0f / qs.x;
        wR[i] = make_float4(qs.x, q1.y*inv0, q2.z*inv0, q3.w*inv0);
    } else if (i < 640) {
        wR[i] = make_float4(0.f, 0.f, 0.f, 0.f);
    } else if (i == 640) {
        float l0 = ik[0], l1 = ik[1], l2 = ik[2], l3 = ik[3];
        float m = fmaxf(fmaxf(l0,l1), fmaxf(l2,l3));
        float e0 = expf(l0-m), e1 = expf(l1-m), e2 = expf(l2-m), e3 = expf(l3-m);
        float inv = 1.0f / (e0+e1+e2+e3);
        float I[4] = { e0*inv, e1*inv, e2*inv, e3*inv };
        #pragma unroll
        for (int s = 0; s < 4; ++s) {
            float4 qs; softrow(tk, s, qs);
            IvecAdj[s] = I[s] / qs.x;
        }
    }
}

// EW table = emission * w0(state), stride-5 pair-reordered, 12 floats/lane
__global__ __launch_bounds__(256) void prep_emis(
    const float* __restrict__ ek, const float4* __restrict__ wR,
    float* __restrict__ emisP)
{
    int tid = blockIdx.x * 256 + threadIdx.x;       // tid = o*768 + q
    if (tid >= 100*SPE) return;
    int q = tid % SPE;
    int o = tid / SPE;
    int ln = q / 12, idx = q % 12;
    float val = 0.0f;
    if (ln < 62 && idx < 10) {
        int j = (idx & 1) ? 5 + (idx >> 1) : (idx >> 1);
        int s = ln*10 + j;
        if (s < S-1) {
            int c = o >> 2, le = o & 3;
            float e;
            if (c == 0) {
                e = 0.25f;
            } else {
                const float* g = ek + s*96 + (c-1)*4;
                float a0=g[0], a1=g[1], a2=g[2], a3=g[3];
                float m = fmaxf(fmaxf(a0,a1), fmaxf(a2,a3));
                float x0=expf(a0-m), x1=expf(a1-m), x2=expf(a2-m), x3=expf(a3-m);
                float inv = 1.0f/(x0+x1+x2+x3);
                e = ((le==0)?x0:(le==1)?x1:(le==2)?x2:x3) * inv;
            }
            val = e * wR[s].x;
        }
    }
    emisP[tid] = val;
}

__global__ __launch_bounds__(256) void extract_obs(
    const float* __restrict__ x, int* __restrict__ obs)
{
    int row  = blockIdx.x * 4 + (threadIdx.x >> 6);
    int lane = threadIdx.x & 63;
    if (row >= NB*TT) return;
    const float* r = x + (size_t)row * 101;
    float acc = r[lane] * (float)lane;
    if (lane < 37) acc += r[64 + lane] * (float)(64 + lane);
    #pragma unroll
    for (int m = 32; m >= 1; m >>= 1) acc += __shfl_xor(acc, m, 64);
    if (lane == 0) obs[row] = (int)(acc + 0.5f);
}

// lane-shift-up-by-1 via DPP wave_shr:1 (VALU pipe); lane 0 -> 0
__device__ __forceinline__ float dpp_up1(float x) {
    int xi = __builtin_bit_cast(int, x);
    int r = __builtin_amdgcn_update_dpp(0, xi, 0x138, 0xF, 0xF, true);
    return __builtin_bit_cast(float, r);
}
template<int CTRL>
__device__ __forceinline__ float dpp_add(float x) {
    int sh = __builtin_amdgcn_update_dpp(0, __builtin_bit_cast(int, x), CTRL, 0xF, 0xF, true);
    return x + __builtin_bit_cast(float, sh);
}
__device__ __forceinline__ float rdlanef(float x, int lane) {
    return __builtin_bit_cast(float, __builtin_amdgcn_readlane(__builtin_bit_cast(int, x), lane));
}

// one HMM step, stride-5 pairs p[j] = (a_j, a_{j+5}); E0..E4 = EW emission pairs.
// Self-loop weight folded into EW: c_k = p_k + sum of ratio-weighted preds.
// pm1 (alpha(611) for lane 0) needs no patch: state 611 never emits -> alpha==0.
#define HMM_COREP(E0,E1,E2,E3,E4)                                            \
  {                                                                          \
    float pm1 = dpp_up1(p[4].y);                                             \
    float pm2 = dpp_up1(p[3].y);                                             \
    float pm3 = dpp_up1(p[2].y);                                             \
    float v610 = rdlanef(p[0].x, 61);                                        \
    float v609 = rdlanef(p[4].y, 60);                                        \
    pm2 = isl0 ? v610 : pm2;                                                 \
    pm3 = isl0 ? v609 : pm3;                                                 \
    float n0x = fmaf(pm1, Wr[0][0].x, p[0].x);                               \
    n0x = fmaf(pm2, Wr[0][1].x, n0x);                                        \
    n0x = fmaf(pm3, Wr[0][2].x, n0x);                                        \
    float n0y = fmaf(p[4].x, Wr[0][0].y, p[0].y);                            \
    n0y = fmaf(p[3].x, Wr[0][1].y, n0y);                                     \
    n0y = fmaf(p[2].x, Wr[0][2].y, n0y);                                     \
    v2f c1 = p[1] + p[0]*Wr[1][0];                                           \
    float n1x = fmaf(pm1, Wr[1][1].x, c1.x);                                 \
    n1x = fmaf(pm2, Wr[1][2].x, n1x);                                        \
    float n1y = fmaf(p[4].x, Wr[1][1].y, c1.y);                              \
    n1y = fmaf(p[3].x, Wr[1][2].y, n1y);                                     \
    v2f c2 = p[2] + p[1]*Wr[2][0] + p[0]*Wr[2][1];                           \
    float n2x = fmaf(pm1, Wr[2][2].x, c2.x);                                 \
    float n2y = fmaf(p[4].x, Wr[2][2].y, c2.y);                              \
    v2f c3 = p[3] + p[2]*Wr[3][0] + p[1]*Wr[3][1] + p[0]*Wr[3][2];           \
    v2f c4 = p[4] + p[3]*Wr[4][0] + p[2]*Wr[4][1] + p[1]*Wr[4][2];           \
    v2f n0; n0.x = n0x; n0.y = n0y;                                          \
    v2f n1; n1.x = n1x; n1.y = n1y;                                          \
    v2f n2; n2.x = n2x; n2.y = n2y;                                          \
    p[0] = n0*(E0); p[1] = n1*(E1); p[2] = n2*(E2);                          \
    p[3] = c3*(E3); p[4] = c4*(E4);                                          \
  }

#define HMM_STEPP(JB) HMM_COREP(eb[JB][0],eb[JB][1],eb[JB][2],eb[JB][3],eb[JB][4])

// refill buffer JB with (pair-reordered) EW row for obs OV; 3 wide loads
#define PREFETCH(JB, OV)                                                     \
  { int _oo = __builtin_amdgcn_readfirstlane(OV);                            \
    const float* _pp = emisP + (size_t)_oo*SPE + 12*l;                       \
    float4 _q0 = *(const float4*)_pp;                                        \
    float4 _q1 = *(const float4*)(_pp+4);                                    \
    float2 _q2 = *(const float2*)(_pp+8);                                    \
    eb[JB][0] = (v2f){_q0.x,_q0.y}; eb[JB][1] = (v2f){_q0.z,_q0.w};          \
    eb[JB][2] = (v2f){_q1.x,_q1.y}; eb[JB][3] = (v2f){_q1.z,_q1.w};          \
    eb[JB][4] = (v2f){_q2.x,_q2.y}; }

#define STEPJ(JB, OV)  HMM_STEPP(JB); PREFETCH(JB, OV);

#define LOCSUM() ({ v2f _t0 = p[0]+p[1]; v2f _t1 = p[2]+p[3];                \
                    _t0 = _t0 + _t1 + p[4]; _t0.x + _t0.y; })

// 16-step renorm block; buffer id = t&7; refills target t+8.
#define GROUP16(C2,C3,N0,N1)                                                 \
    STEPJ(0, (C2).x); zl = dpp_add<0x111>(zl);                               \
    STEPJ(1, (C2).y); zl = dpp_add<0x112>(zl);                               \
    STEPJ(2, (C2).z); zl = dpp_add<0x114>(zl);                               \
    STEPJ(3, (C2).w); zl = dpp_add<0x118>(zl);                               \
    STEPJ(4, (C3).x); zl = dpp_add<0x142>(zl);                               \
    STEPJ(5, (C3).y); zl = dpp_add<0x143>(zl);                               \
    STEPJ(6, (C3).z);                                                        \
    STEPJ(7, (C3).w);                                                        \
    STEPJ(0, (N0).x);                                                        \
    STEPJ(1, (N0).y);                                                        \
    STEPJ(2, (N0).z);                                                        \
    STEPJ(3, (N0).w);                                                        \
    STEPJ(4, (N1).x);                                                        \
    {                                                                        \
      float z    = rdlanef(zl, 63);                                          \
      float inv_ = __builtin_amdgcn_rcpf(z);                                 \
      float lg_  = __logf(z);                                                \
      STEPJ(5, (N1).y);                                                      \
      STEPJ(6, (N1).z);                                                      \
      v2f ivP; ivP.x = inv_; ivP.y = inv_;                                   \
      v2f ep0=eb[7][0]*ivP, ep1=eb[7][1]*ivP, ep2=eb[7][2]*ivP;              \
      v2f ep3=eb[7][3]*ivP, ep4=eb[7][4]*ivP;                                \
      HMM_COREP(ep0,ep1,ep2,ep3,ep4);                                        \
      PREFETCH(7, (N1).w);                                                   \
      ll += lg_;                                                             \
    }                                                                        \
    zl = LOCSUM();

// one wave per batch; no LDS; obs via uniform int4 blocks (scalar loads)
__global__ __launch_bounds__(64) void forward(
    const float* __restrict__ emisP, const float4* __restrict__ wR,
    const float* __restrict__ IvecAdj, const int* __restrict__ obs,
    float* __restrict__ out)
{
    const int l = threadIdx.x;
    const int b = blockIdx.x;
    const bool isl0 = (l == 0);
    const int* obp = obs + b * TT;

    // per-lane ratio weights, stride-5 pairs: Wr[j][m-1] = (r_m(10l+j), r_m(10l+j+5))
    v2f Wr[5][3];
    {
        float4 w[10];
        #pragma unroll
        for (int k = 0; k < 10; ++k) w[k] = wR[10*l + k];
        #pragma unroll
        for (int j = 0; j < 5; ++j) {
            Wr[j][0].x = w[j].y; Wr[j][0].y = w[j+5].y;
            Wr[j][1].x = w[j].z; Wr[j][1].y = w[j+5].z;
            Wr[j][2].x = w[j].w; Wr[j][2].y = w[j+5].w;
        }
    }

    // obs blocks (uniform -> scalar regs)
    int4 c0_, c1_, c2_, c3_, n0_, n1_, n2_, n3_;
    {
        const int4* o4 = (const int4*)obp;
        c0_ = o4[0]; c1_ = o4[1]; c2_ = o4[2]; c3_ = o4[3];
        n0_ = o4[4]; n1_ = o4[5]; n2_ = o4[6]; n3_ = o4[7];
    }

    v2f p[5];
    float ll = 0.0f;
    v2f eb[8][5];

    // t = 0: alpha0 = I * E = IvecAdj * EW  (w0 cancels)
    {
        int o0 = __builtin_amdgcn_readfirstlane(c0_.x);
        const float* ep = emisP + (size_t)o0*SPE + 12*l;
        float e0 = ep[0], e1 = ep[2], e2 = ep[4], e3 = ep[6];
        p[0].x = isl0 ? e0*IvecAdj[0] : 0.f;  p[0].y = 0.f;
        p[1].x = isl0 ? e1*IvecAdj[1] : 0.f;  p[1].y = 0.f;
        p[2].x = isl0 ? e2*IvecAdj[2] : 0.f;  p[2].y = 0.f;
        p[3].x = isl0 ? e3*IvecAdj[3] : 0.f;  p[3].y = 0.f;
        p[4].x = 0.f; p[4].y = 0.f;
    }
    float zl = LOCSUM();

    // initial buffers for t = 1..8 (ids 1..7,0)
    PREFETCH(1, c0_.y); PREFETCH(2, c0_.z); PREFETCH(3, c0_.w);
    PREFETCH(4, c1_.x); PREFETCH(5, c1_.y); PREFETCH(6, c1_.z); PREFETCH(7, c1_.w);
    PREFETCH(0, c2_.x);

    // prologue: steps t = 1..15 (fold at t=15)
    STEPJ(1, c2_.y); zl = dpp_add<0x111>(zl);
    STEPJ(2, c2_.z); zl = dpp_add<0x112>(zl);
    STEPJ(3, c2_.w); zl = dpp_add<0x114>(zl);
    STEPJ(4, c3_.x); zl = dpp_add<0x118>(zl);
    STEPJ(5, c3_.y); zl = dpp_add<0x142>(zl);
    STEPJ(6, c3_.z); zl = dpp_add<0x143>(zl);
    STEPJ(7, c3_.w);
    STEPJ(0, n0_.x);
    STEPJ(1, n0_.y);
    STEPJ(2, n0_.z);
    STEPJ(3, n0_.w);
    STEPJ(4, n1_.x);
    {
      float z    = rdlanef(zl, 63);
      float inv_ = __builtin_amdgcn_rcpf(z);
      float lg_  = __logf(z);
      STEPJ(5, n1_.y);
      STEPJ(6, n1_.z);
      v2f ivP; ivP.x = inv_; ivP.y = inv_;
      v2f ep0=eb[7][0]*ivP, ep1=eb[7][1]*ivP, ep2=eb[7][2]*ivP;
      v2f ep3=eb[7][3]*ivP, ep4=eb[7][4]*ivP;
      HMM_COREP(ep0,ep1,ep2,ep3,ep4);
      PREFETCH(7, n1_.w);
      ll += lg_;
    }
    zl = LOCSUM();

    // main: 511 blocks of 16 steps (t = 16..8191)
    #pragma unroll 1
    for (int g = 1; g < 512; ++g) {
        c2_ = n2_; c3_ = n3_;
        const int4* o4n = (const int4*)(obp + ((g < 511) ? (g+1)*16 : 8176));
        n0_ = o4n[0]; n1_ = o4n[1]; n2_ = o4n[2]; n3_ = o4n[3];
        GROUP16(c2_, c3_, n0_, n1_);
    }

    // final: z of the last block
    {
        float zf = zl;
        zf = dpp_add<0x111>(zf);
        zf = dpp_add<0x112>(zf);
        zf = dpp_add<0x114>(zf);
        zf = dpp_add<0x118>(zf);
        zf = dpp_add<0x142>(zf);
        zf = dpp_add<0x143>(zf);
        ll += __logf(rdlanef(zf, 63));
    }
    if (isl0) out[b] = ll;
}

extern "C" void kernel_launch(void* const* d_in, const int* in_sizes, int n_in,
                              void* d_out, int out_size, void* d_ws, size_t ws_size,
                              hipStream_t stream)
{
    const float* x  = (const float*)d_in[0];   // inputs [32,8192,101]
    const float* ik = (const float*)d_in[1];   // init_kernel [4]
    const float* tk = (const float*)d_in[2];   // transition_kernel [1836]
    const float* ek = (const float*)d_in[3];   // emission_kernel [58656]
    float* out = (float*)d_out;

    char* ws = (char*)d_ws;
    float4* wR      = (float4*)(ws + WR_OFF);
    float*  IvecAdj = (float*)(ws + IV_OFF);
    float*  emisP   = (float*)(ws + EMIS_OFF);
    int*    obs     = (int*)(ws + OBS_OFF);

    hipLaunchKernelGGL(prep_tables, dim3(3), dim3(256), 0, stream, tk, ik, wR, IvecAdj);
    hipLaunchKernelGGL(prep_emis, dim3((100*SPE + 255)/256), dim3(256), 0, stream,
                       ek, (const float4*)wR, emisP);
    hipLaunchKernelGGL(extract_obs, dim3((NB*TT + 3)/4), dim3(256), 0, stream, x, obs);
    hipLaunchKernelGGL(forward, dim3(NB), dim3(64), 0, stream,
                       emisP, (const float4*)wR, IvecAdj, obs, out);
}